// Round 9
// baseline (168.833 us; speedup 1.0000x reference)
//
#include <hip/hip_runtime.h>
#include <hip/hip_bf16.h>

// PFNN: out[n][b] = L3(tanh(L2(tanh(L1(tanh(L0(x)))))))  B=4, H=32, D_IN=3,
// N=1048576.  f16 MFMA 16x16x32 computing out^T = W^T h^T per 16-pt subtile.
// R8 vs R7 (105us; busy-time pinned ~84-90us across R1/R4/R6/R7 despite a
// 2x trans cut => issued stream ~2x source-level count; attack the glue):
//  - s-loop fully unrolled; xf/w0 fragments hoisted OUT of it (VGPR was 44
//    of a 128 cap -- R6's in-loop re-assembly saved registers we don't need).
//  - deg-4 poly of (1-e)/(1+e) restored (absmax headroom: R7's deg-3 was at
//    60% of threshold for zero speed gain).
//  - keep: f16 exp2 (one v_or builds -|y| pair; pkrtz doubles as sign src),
//    permlane32/16_swap redistribution, bias in MFMA C / W0 k=3 row,
//    one 64-pt tile per wave, launch_bounds(256,4), single float4 store.
// Weights/biases of L0..L2 pre-scaled by 2*log2(e) so y is in exp2 domain.

#define NPTS 1048576
constexpr int BLOCK_THREADS = 256;           // 4 waves = 1 wave/SIMD
constexpr int GRID_BLOCKS = NPTS / 64 / 4;   // 4096: one 64-pt tile per wave
constexpr float TANH_SCALE = 2.885390081777927f;  // 2*log2(e)

typedef _Float16 h8v __attribute__((ext_vector_type(8)));
typedef _Float16 h2v __attribute__((ext_vector_type(2)));
typedef float f4v __attribute__((ext_vector_type(4)));
typedef unsigned int u2v __attribute__((ext_vector_type(2)));

union H8 { h8v h; int i[4]; };

extern "C" __device__ _Float16 __ocml_exp2_f16(_Float16);

__device__ __forceinline__ int pkrtz(float a, float b) {
  return __builtin_bit_cast(int, __builtin_amdgcn_cvt_pkrtz(a, b));
}

// Packed tanh of 2 f32 values.  ypk = f16 pair of (y0,y1); e = 2^(-|y|) via
// v_exp_f16 (one v_or builds the negated-abs pair); deg-4 minimax poly of
// (1-e)/(1+e) on [0,1]; sign re-inserted from ypk via bfi.
__device__ __forceinline__ int tanh2e(float y0, float y1) {
  int ypk = pkrtz(y0, y1);
  int yn = ypk | 0x80008000;                        // -|y| per half
  h2v yv = __builtin_bit_cast(h2v, yn);
  h2v e;
  e[0] = __ocml_exp2_f16(yv[0]);
  e[1] = __ocml_exp2_f16(yv[1]);
  h2v t = e * (_Float16)0.3137280f + (_Float16)-1.0845760f;
  t = e * t + (_Float16)1.7439296f;
  t = e * t + (_Float16)-1.9722144f;
  t = e * t + (_Float16)0.9994922f;
  int gi = __builtin_bit_cast(int, t);
  return (ypk & 0x80008000) | (gi & 0x7fff7fff);    // copysign (v_bfi)
}

// tanh both accumulator tiles (8 f32), pack, redistribute into next B-frag.
// Quadrant Qi of the wave holds tile0 pairs (A0,A1), tile1 pairs (B0,B1);
// w0=[A0Q0,A0Q2,B0Q0,B0Q2] etc = swap16(swap32(A0,B0)) / swap16(swap32(A1,B1)).
__device__ __forceinline__ H8 make_bfrag(f4v a0, f4v a1) {
  int A0 = tanh2e(a0[0], a0[1]);   // tile0 units (4i,4i+1)
  int A1 = tanh2e(a0[2], a0[3]);   // tile0 units (4i+2,4i+3)
  int B0 = tanh2e(a1[0], a1[1]);   // tile1
  int B1 = tanh2e(a1[2], a1[3]);
  u2v sA = __builtin_amdgcn_permlane32_swap((unsigned)A0, (unsigned)B0, false, false);
  u2v wA = __builtin_amdgcn_permlane16_swap(sA[0], sA[1], false, false);
  u2v sB = __builtin_amdgcn_permlane32_swap((unsigned)A1, (unsigned)B1, false, false);
  u2v wB = __builtin_amdgcn_permlane16_swap(sB[0], sB[1], false, false);
  H8 hf;
  hf.i[0] = (int)wA[0];
  hf.i[1] = (int)wB[0];
  hf.i[2] = (int)wA[1];
  hf.i[3] = (int)wB[1];
  return hf;
}

extern "C" __global__ void __launch_bounds__(BLOCK_THREADS, 4) pfnn_kernel(
    const float* __restrict__ X,
    const float* __restrict__ W0, const float* __restrict__ B0,
    const float* __restrict__ W1, const float* __restrict__ B1,
    const float* __restrict__ W2, const float* __restrict__ B2,
    const float* __restrict__ W3, const float* __restrict__ B3,
    float* __restrict__ Out) {
  __shared__ alignas(16) _Float16 lWT0[4][32][4];    // [b][u][k] k<3: s*W0, k==3: s*b0
  __shared__ alignas(16) _Float16 lWT1[4][32][40];   // [b][u][k], rows padded to 80B
  __shared__ alignas(16) _Float16 lWT2[4][32][40];
  __shared__ alignas(16) float lB1[4][32];           // s*b1 (MFMA C operand)
  __shared__ alignas(16) float lB2[4][32];
  __shared__ alignas(16) _Float16 lW3h[4][32];       // raw W3 (L3 has no tanh)
  __shared__ float lb3[4];

  const int tid = threadIdx.x;
  for (int idx = tid; idx < 512; idx += BLOCK_THREADS) {
    int b = idx >> 7, u = (idx >> 2) & 31, k = idx & 3;
    float v = (k < 3) ? W0[(b * 3 + k) * 32 + u] : B0[b * 32 + u];
    lWT0[b][u][k] = (_Float16)(v * TANH_SCALE);
  }
  for (int idx = tid; idx < 4096; idx += BLOCK_THREADS) {
    int b = idx >> 10, k = (idx >> 5) & 31, u = idx & 31;
    lWT1[b][u][k] = (_Float16)(W1[idx] * TANH_SCALE);
    lWT2[b][u][k] = (_Float16)(W2[idx] * TANH_SCALE);
  }
  for (int idx = tid; idx < 128; idx += BLOCK_THREADS) {
    int b = idx >> 5, u = idx & 31;
    lB1[b][u] = B1[idx] * TANH_SCALE;
    lB2[b][u] = B2[idx] * TANH_SCALE;
    lW3h[b][u] = (_Float16)W3[idx];
  }
  if (tid < 4) lb3[tid] = B3[tid];
  __syncthreads();

  const int lane = tid & 63;
  const int wv = tid >> 6;       // 0..3
  const int g = lane >> 4;       // k-group
  const int p = lane & 15;       // point within subtile
  const bool g0 = (g == 0);
  const int addrP = p << 2;      // gather: src lane p

  const int blk = blockIdx.x * 4 + wv;   // one 64-point tile per wave
  const int base = blk << 6;
  const float* xp = X + (size_t)(base + lane) * 3;
  float x0 = xp[0], x1 = xp[1], x2 = xp[2];

  // Branch-independent x B-fragments, fully materialized (16 VGPR).  g>0
  // lanes hold junk in words 0,1: those B rows meet the zeroed g>0 columns
  // of the W0 A-fragment, so no select is needed.
  H8 xf[4];
#pragma unroll
  for (int s = 0; s < 4; ++s) {
    int a = (16 * s + p) << 2;
    float fx0 = __int_as_float(__builtin_amdgcn_ds_bpermute(a, __float_as_int(x0)));
    float fx1 = __int_as_float(__builtin_amdgcn_ds_bpermute(a, __float_as_int(x1)));
    float fx2 = __int_as_float(__builtin_amdgcn_ds_bpermute(a, __float_as_int(x2)));
    xf[s].i[0] = pkrtz(fx0, fx1);
    xf[s].i[1] = pkrtz(fx2, 1.0f);
    xf[s].i[2] = 0;
    xf[s].i[3] = 0;
  }
  const f4v z = {0.f, 0.f, 0.f, 0.f};

  f4v res4;
#pragma unroll
  for (int b = 0; b < 4; ++b) {
    // Hoisted per-branch weight fragments.
    H8 w0a[2];
    h8v w1a[2], w2a[2];
    f4v bs1[2], bs2[2];
#pragma unroll
    for (int t = 0; t < 2; ++t) {
      const int* q = (const int*)&lWT0[b][16 * t + p][0];
      w0a[t].i[0] = g0 ? q[0] : 0;
      w0a[t].i[1] = g0 ? q[1] : 0;
      w0a[t].i[2] = 0;
      w0a[t].i[3] = 0;
      w1a[t] = *(const h8v*)&lWT1[b][16 * t + p][8 * g];
      w2a[t] = *(const h8v*)&lWT2[b][16 * t + p][8 * g];
      bs1[t] = *(const f4v*)&lB1[b][16 * t + 4 * g];
      bs2[t] = *(const f4v*)&lB2[b][16 * t + 4 * g];
    }
    // L3 A-fragment: W3^T in row 0 (lanes with p==0 hold w3[8g..8g+7]).
    h8v w3z = {0, 0, 0, 0, 0, 0, 0, 0};
    h8v w3a = (p == 0) ? *(const h8v*)&lW3h[b][8 * g] : w3z;
    float b3s = lb3[b];
    float res = 0.0f;

#pragma unroll     // FULL unroll: straight-line region per branch
    for (int s = 0; s < 4; ++s) {
      // L0 (bias folded in k==3 row of W0')
      f4v a0 = __builtin_amdgcn_mfma_f32_16x16x32_f16(w0a[0].h, xf[s].h, z, 0, 0, 0);
      f4v a1 = __builtin_amdgcn_mfma_f32_16x16x32_f16(w0a[1].h, xf[s].h, z, 0, 0, 0);
      H8 hf = make_bfrag(a0, a1);
      // L1
      a0 = __builtin_amdgcn_mfma_f32_16x16x32_f16(w1a[0], hf.h, bs1[0], 0, 0, 0);
      a1 = __builtin_amdgcn_mfma_f32_16x16x32_f16(w1a[1], hf.h, bs1[1], 0, 0, 0);
      hf = make_bfrag(a0, a1);
      // L2
      a0 = __builtin_amdgcn_mfma_f32_16x16x32_f16(w2a[0], hf.h, bs2[0], 0, 0, 0);
      a1 = __builtin_amdgcn_mfma_f32_16x16x32_f16(w2a[1], hf.h, bs2[1], 0, 0, 0);
      hf = make_bfrag(a0, a1);
      // L3: one MFMA; row 0 (reg 0, lanes 0..15) = out[point p]
      f4v o = __builtin_amdgcn_mfma_f32_16x16x32_f16(w3a, hf.h, z, 0, 0, 0);
      // Lane l=16g+p needs subtile g's value for point p (lives in lane p).
      float rr = __int_as_float(__builtin_amdgcn_ds_bpermute(addrP, __float_as_int(o[0])));
      res = (g == s) ? rr : res;
    }
    res4[b] = res + b3s;
  }
  *(f4v*)(Out + (size_t)(base + lane) * 4) = res4;   // one 16B store/point
}

extern "C" void kernel_launch(void* const* d_in, const int* in_sizes, int n_in,
                              void* d_out, int out_size, void* d_ws, size_t ws_size,
                              hipStream_t stream) {
  (void)in_sizes; (void)n_in; (void)out_size; (void)d_ws; (void)ws_size;
  const float* X  = (const float*)d_in[0];
  const float* W0 = (const float*)d_in[1];
  const float* B0 = (const float*)d_in[2];
  const float* W1 = (const float*)d_in[3];
  const float* B1 = (const float*)d_in[4];
  const float* W2 = (const float*)d_in[5];
  const float* B2 = (const float*)d_in[6];
  const float* W3 = (const float*)d_in[7];
  const float* B3 = (const float*)d_in[8];
  float* Out = (float*)d_out;
  pfnn_kernel<<<dim3(GRID_BLOCKS), dim3(BLOCK_THREADS), 0, stream>>>(
      X, W0, B0, W1, B1, W2, B2, W3, B3, Out);
}